// Round 1
// baseline (84.865 us; speedup 1.0000x reference)
//
#include <hip/hip_runtime.h>

// Problem constants
#define X_RANGE 256
#define Y_RANGE 256
#define NUM_ANGLES 180
#define NUM_DET 512
#define BATCH 8
#define M_ROWS (BATCH * NUM_ANGLES)      // 1440
#define K_DIM NUM_DET                    // 512
#define N_DIM NUM_DET                    // 512
#define AD (NUM_ANGLES * NUM_DET)        // 92160
#define NPIX (X_RANGE * Y_RANGE)         // 65536

// ---------------- Kernel 1: filter GEMM ----------------
// out[m][e] = sum_d A[m][d] * W[e][d]   (both operands K-contiguous)
// m = b*180 + a, so out row-major == flat [b][a*512+e] layout the gather needs.
#define BM 64
#define BN 64
#define BK 32

__global__ __launch_bounds__(256) void filter_gemm(const float* __restrict__ A,
                                                   const float* __restrict__ Wm,
                                                   float* __restrict__ outF) {
    __shared__ float As[BK][BM];   // transposed: As[k][m]
    __shared__ float Bs[BK][BN];   // transposed: Bs[k][n]
    const int tid = threadIdx.x;
    const int tx = tid & 15;       // n direction (4 cols each)
    const int ty = tid >> 4;       // m direction (4 rows each)
    const int mBase = blockIdx.x * BM;
    const int nBase = blockIdx.y * BN;

    float acc[4][4] = {};

    for (int k0 = 0; k0 < K_DIM; k0 += BK) {
        // Stage A tile (64 m x 32 k) and B tile (64 n x 32 k), transposed into LDS.
        // 512 float4 per tile, 2 per thread.
#pragma unroll
        for (int l = 0; l < 2; ++l) {
            const int lin = tid + l * 256;
            const int r  = lin >> 3;       // row within tile (m or n), 0..63
            const int kq = lin & 7;        // which float4 along k
            const int gm = mBase + r;
            float4 v = make_float4(0.f, 0.f, 0.f, 0.f);
            if (gm < M_ROWS)
                v = *reinterpret_cast<const float4*>(A + (size_t)gm * K_DIM + k0 + (kq << 2));
            As[(kq << 2) + 0][r] = v.x;
            As[(kq << 2) + 1][r] = v.y;
            As[(kq << 2) + 2][r] = v.z;
            As[(kq << 2) + 3][r] = v.w;
            const float4 w = *reinterpret_cast<const float4*>(
                Wm + (size_t)(nBase + r) * K_DIM + k0 + (kq << 2));
            Bs[(kq << 2) + 0][r] = w.x;
            Bs[(kq << 2) + 1][r] = w.y;
            Bs[(kq << 2) + 2][r] = w.z;
            Bs[(kq << 2) + 3][r] = w.w;
        }
        __syncthreads();
#pragma unroll
        for (int k = 0; k < BK; ++k) {
            const float4 a4 = *reinterpret_cast<const float4*>(&As[k][ty << 2]);
            const float4 b4 = *reinterpret_cast<const float4*>(&Bs[k][tx << 2]);
            const float av[4] = {a4.x, a4.y, a4.z, a4.w};
            const float bv[4] = {b4.x, b4.y, b4.z, b4.w};
#pragma unroll
            for (int i = 0; i < 4; ++i)
#pragma unroll
                for (int j = 0; j < 4; ++j)
                    acc[i][j] += av[i] * bv[j];
        }
        __syncthreads();
    }

#pragma unroll
    for (int i = 0; i < 4; ++i) {
        const int gm = mBase + (ty << 2) + i;
        if (gm < M_ROWS) {
            const float4 o = make_float4(acc[i][0], acc[i][1], acc[i][2], acc[i][3]);
            *reinterpret_cast<float4*>(outF + (size_t)gm * N_DIM + nBase + (tx << 2)) = o;
        }
    }
}

// ---------------- Kernel 2: gather + weighted backprojection ----------------
// One thread per pixel p (= x*256+y, matching coord_mat's flat row layout).
// Rows of coord_mat/weights are 180 elements = 720 B, 16B-aligned -> int4/float4.
__global__ __launch_bounds__(256) void backproject(const float* __restrict__ fil,
                                                   const float* __restrict__ wts,
                                                   const int* __restrict__ cm,
                                                   float* __restrict__ out) {
    const int p = blockIdx.x * blockDim.x + threadIdx.x;   // 0..65535
    const int4*   cm4 = reinterpret_cast<const int4*>(cm + (size_t)p * NUM_ANGLES);
    const float4* w4  = reinterpret_cast<const float4*>(wts + (size_t)p * NUM_ANGLES);

    float acc[BATCH] = {};
#pragma unroll 3
    for (int i = 0; i < NUM_ANGLES / 4; ++i) {     // 45 iterations
        const int4   c = cm4[i];
        const float4 w = w4[i];
        const int   idx[4] = {c.x, c.y, c.z, c.w};
        const float wv[4]  = {w.x, w.y, w.z, w.w};
#pragma unroll
        for (int j = 0; j < 4; ++j) {
#pragma unroll
            for (int b = 0; b < BATCH; ++b)
                acc[b] += fil[(size_t)b * AD + idx[j]] * wv[j];
        }
    }
#pragma unroll
    for (int b = 0; b < BATCH; ++b)
        out[(size_t)b * NPIX + p] = acc[b];
}

extern "C" void kernel_launch(void* const* d_in, const int* in_sizes, int n_in,
                              void* d_out, int out_size, void* d_ws, size_t ws_size,
                              hipStream_t stream) {
    const float* sino = (const float*)d_in[0];   // [8,1,180,512] f32
    const float* Wm   = (const float*)d_in[1];   // [512,512] f32
    const float* wts  = (const float*)d_in[2];   // [1,1,256,256,180] f32
    const int*   cm   = (const int*)d_in[3];     // [256,256,180] i32
    float* out = (float*)d_out;                  // [8,1,256,256] f32
    float* fil = (float*)d_ws;                   // 1440*512 f32 = 2.95 MB scratch

    dim3 gridG((M_ROWS + BM - 1) / BM, N_DIM / BN);   // 23 x 8
    filter_gemm<<<gridG, dim3(256), 0, stream>>>(sino, Wm, fil);

    backproject<<<NPIX / 256, 256, 0, stream>>>(fil, wts, cm, out);
}